// Round 1
// baseline (2392.950 us; speedup 1.0000x reference)
//
#include <hip/hip_runtime.h>
#include <stdint.h>

// ---- problem constants ----
#define HID   3072
#define LSEQ  2304
#define NH    24
#define HD    128
#define N1    21504   // 3*HID + MLP
#define QKVW  9216    // 3*HID
#define X2W   15360   // HID + MLP

typedef __bf16 bf16x8 __attribute__((ext_vector_type(8)));
typedef unsigned short u16x8 __attribute__((ext_vector_type(8)));
typedef float f32x4 __attribute__((ext_vector_type(4)));

#define MFMA(a,b,c) __builtin_amdgcn_mfma_f32_16x16x32_bf16((a),(b),(c),0,0,0)

__device__ __forceinline__ unsigned short f2b(float f){
  unsigned int u = __builtin_bit_cast(unsigned int, f);
  u += 0x7fffu + ((u >> 16) & 1u);   // RTNE
  return (unsigned short)(u >> 16);
}
__device__ __forceinline__ float b2f(unsigned short b){
  return __builtin_bit_cast(float, ((unsigned int)b) << 16);
}
__device__ __forceinline__ unsigned int pk2(float lo, float hi){
  return (unsigned int)f2b(lo) | ((unsigned int)f2b(hi) << 16);
}

// ---------------- silu(temb) ----------------
__global__ void silu_k(const float* __restrict__ temb, float* __restrict__ st){
  int i = blockIdx.x*256 + threadIdx.x;
  if (i < HID){ float x = temb[i]; st[i] = x / (1.f + __expf(-x)); }
}

// ---------------- emb = silu(temb) @ ada_w + ada_b ----------------
// grid 288, block 256: 32 output cols per block, 8-way K-split per col
__global__ __launch_bounds__(256) void ada_k(const float* __restrict__ st,
                                             const float* __restrict__ aw,
                                             const float* __restrict__ ab,
                                             float* __restrict__ emb){
  int c = threadIdx.x & 31, g = threadIdx.x >> 5;
  int col = blockIdx.x*32 + c;
  float acc = 0.f;
  for (int k = g; k < HID; k += 8)
    acc += st[k] * aw[(size_t)k*QKVW + col];
  __shared__ float part[256];
  part[threadIdx.x] = acc;
  __syncthreads();
  if (threadIdx.x < 32){
    float s = 0.f;
    #pragma unroll
    for (int j = 0; j < 8; ++j) s += part[j*32 + threadIdx.x];
    int cc = blockIdx.x*32 + threadIdx.x;
    emb[cc] = s + ab[cc];
  }
}

// ---------------- LayerNorm + (1+scale)/shift modulation -> bf16 ----------------
__global__ __launch_bounds__(256) void ln_k(const float* __restrict__ hs,
                                            const float* __restrict__ emb,
                                            unsigned short* __restrict__ nx){
  int l = blockIdx.x, t = threadIdx.x;
  const float* row = hs + (size_t)l*HID;
  float x[12], s = 0.f, ss = 0.f;
  #pragma unroll
  for (int i = 0; i < 12; ++i){ x[i] = row[t + i*256]; s += x[i]; ss += x[i]*x[i]; }
  #pragma unroll
  for (int off = 32; off; off >>= 1){ s += __shfl_xor(s, off); ss += __shfl_xor(ss, off); }
  __shared__ float red[8];
  int w = t >> 6, lane = t & 63;
  if (!lane){ red[w] = s; red[4+w] = ss; }
  __syncthreads();
  s = red[0]+red[1]+red[2]+red[3];
  ss = red[4]+red[5]+red[6]+red[7];
  float mu = s * (1.f/HID);
  float var = ss * (1.f/HID) - mu*mu;
  float rstd = rsqrtf(var + 1e-6f);
  #pragma unroll
  for (int i = 0; i < 12; ++i){
    int c = t + i*256;
    float v = (x[i]-mu)*rstd*(1.f + emb[HID + c]) + emb[c];
    nx[(size_t)l*HID + c] = f2b(v);
  }
}

// ---------------- MFMA GEMM: C = A(bf16)[M,K] @ B(f32)[K,N] + bias, fused epilogues ----------------
// EPI=1: lin1 -> qkv (cols<9216) and gelu(mlp) into X2[:,3072+..]
// EPI=2: lin2 -> out = hidden + (acc+bias)*gate
template<int EPI>
__global__ __launch_bounds__(256)
void gemm_k(const unsigned short* __restrict__ A, const float* __restrict__ B,
            const float* __restrict__ bias, int K, int N,
            unsigned short* __restrict__ oq, unsigned short* __restrict__ ox2,
            float* __restrict__ of, const float* __restrict__ hid,
            const float* __restrict__ emb)
{
  __shared__ __align__(16) unsigned short As[128*32];   // [m][k]
  __shared__ __align__(16) unsigned short Bs[32*128];   // [k][n]
  const int t = threadIdx.x;
  const int m0 = blockIdx.y * 128, n0 = blockIdx.x * 128;
  const int w = t >> 6, lane = t & 63, quad = lane >> 4, l16 = lane & 15;
  const int wm = w >> 1, wn = w & 1;

  f32x4 acc[4][4];
  #pragma unroll
  for (int i = 0; i < 4; ++i)
    #pragma unroll
    for (int j = 0; j < 4; ++j) acc[i][j] = (f32x4){0.f,0.f,0.f,0.f};

  const int arow = t >> 2, ach = t & 3;   // A: 64 rows x 4 chunks per pass
  const int krow = t >> 3, ng = t & 7;    // B: 32 rows x 8 groups of 16 floats
  const unsigned short* aptr = A + (size_t)(m0 + arow) * K + ach*8;
  const float* bptr = B + (size_t)krow * N + n0 + ng*16;

  for (int k0 = 0; k0 < K; k0 += 32){
    __syncthreads();
    { // stage A (coalesced 16B, contiguous LDS)
      uint4 v0 = *(const uint4*)(aptr + k0);
      uint4 v1 = *(const uint4*)(aptr + (size_t)64*K + k0);
      *(uint4*)&As[arow*32 + ach*8] = v0;
      *(uint4*)&As[(arow+64)*32 + ach*8] = v1;
    }
    { // stage B: fp32 load, cvt->bf16, contiguous LDS write
      const float* bp = bptr + (size_t)k0 * N;
      float4 f0 = *(const float4*)(bp);
      float4 f1 = *(const float4*)(bp+4);
      float4 f2 = *(const float4*)(bp+8);
      float4 f3 = *(const float4*)(bp+12);
      uint4 w0 = { pk2(f0.x,f0.y), pk2(f0.z,f0.w), pk2(f1.x,f1.y), pk2(f1.z,f1.w) };
      uint4 w1 = { pk2(f2.x,f2.y), pk2(f2.z,f2.w), pk2(f3.x,f3.y), pk2(f3.z,f3.w) };
      *(uint4*)&Bs[krow*128 + ng*16]     = w0;
      *(uint4*)&Bs[krow*128 + ng*16 + 8] = w1;
    }
    __syncthreads();
    bf16x8 af[4], bfr[4];
    #pragma unroll
    for (int mt = 0; mt < 4; ++mt)
      af[mt] = __builtin_bit_cast(bf16x8, *(const uint4*)&As[(wm*64 + mt*16 + l16)*32 + quad*8]);
    #pragma unroll
    for (int nt = 0; nt < 4; ++nt){
      u16x8 r;
      #pragma unroll
      for (int j = 0; j < 8; ++j) r[j] = Bs[(quad*8 + j)*128 + wn*64 + nt*16 + l16];
      bfr[nt] = __builtin_bit_cast(bf16x8, r);
    }
    #pragma unroll
    for (int mt = 0; mt < 4; ++mt)
      #pragma unroll
      for (int nt = 0; nt < 4; ++nt)
        acc[mt][nt] = MFMA(af[mt], bfr[nt], acc[mt][nt]);
  }

  // epilogue (C/D layout: col = lane&15, row = quad*4 + r)
  #pragma unroll
  for (int mt = 0; mt < 4; ++mt){
    #pragma unroll
    for (int nt = 0; nt < 4; ++nt){
      const int gn = n0 + wn*64 + nt*16 + l16;
      const float bs = bias[gn];
      #pragma unroll
      for (int r = 0; r < 4; ++r){
        const int gm = m0 + wm*64 + mt*16 + quad*4 + r;
        float v = acc[mt][nt][r] + bs;
        if (EPI == 1){
          if (gn < QKVW){
            oq[(size_t)gm*QKVW + gn] = f2b(v);
          } else {
            // tanh-gelu; th = 1 - 2/(e^{2u}+1) is overflow-safe
            float e = __expf(1.5957691216057308f*(v + 0.044715f*v*v*v));
            float th = 1.f - 2.f/(e + 1.f);
            ox2[(size_t)gm*X2W + HID + (gn - QKVW)] = f2b(0.5f*v*(1.f + th));
          }
        } else {
          of[(size_t)gm*HID + gn] = hid[(size_t)gm*HID + gn] + v * emb[2*HID + gn];
        }
      }
    }
  }
}

// ---------------- q/k RMSNorm + RoPE (in place on qkv), fold 1/sqrt(HD) into q ----------------
__global__ __launch_bounds__(256) void qknorm_k(unsigned short* __restrict__ qkv,
                                                const float* __restrict__ qn,
                                                const float* __restrict__ kn,
                                                const float* __restrict__ cosp,
                                                const float* __restrict__ sinp,
                                                const int* __restrict__ txtp){
  int img = LSEQ - txtp[0];
  int rid = blockIdx.x*4 + (threadIdx.x >> 6);
  int lane = threadIdx.x & 63;
  int which = rid / (NH*LSEQ);
  int rem   = rid % (NH*LSEQ);
  int h = rem / LSEQ, l = rem % LSEQ;
  unsigned short* p = qkv + (size_t)l*QKVW + which*HID + h*HD + lane*2;
  unsigned int both = *(const unsigned int*)p;
  float x0 = b2f((unsigned short)(both & 0xffffu));
  float x1 = b2f((unsigned short)(both >> 16));
  float ss = x0*x0 + x1*x1;
  #pragma unroll
  for (int off = 32; off; off >>= 1) ss += __shfl_xor(ss, off);
  float r = rsqrtf(ss*(1.f/HD) + 1e-6f);
  const float* wv = which ? kn : qn;
  float y0 = x0*r*wv[lane*2], y1 = x1*r*wv[lane*2+1];
  if (l < img){
    float c0 = cosp[l*HD + lane*2], c1 = cosp[l*HD + lane*2 + 1];
    float s0 = sinp[l*HD + lane*2], s1 = sinp[l*HD + lane*2 + 1];
    float t0 = y0*c0 - y1*s0;
    float t1 = y1*c1 + y0*s1;
    y0 = t0; y1 = t1;
  }
  if (which == 0){ y0 *= 0.08838834764831845f; y1 *= 0.08838834764831845f; }
  *(unsigned int*)p = pk2(y0, y1);
}

// ---------------- V transpose: qkv v-part [l][h*128+d] -> vT[h][d][l] ----------------
__global__ __launch_bounds__(256) void vtrans_k(const unsigned short* __restrict__ qkv,
                                                unsigned short* __restrict__ vT){
  __shared__ __align__(16) unsigned short Ls[64*136];
  int h = blockIdx.y, m0 = blockIdx.x*64, t = threadIdx.x;
  #pragma unroll
  for (int p = 0; p < 4; ++p){
    int lin = p*256 + t, m = lin >> 4, ch = lin & 15;
    *(uint4*)&Ls[m*136 + ch*8] =
      *(const uint4*)(qkv + (size_t)(m0+m)*QKVW + 2*HID + h*HD + ch*8);
  }
  __syncthreads();
  #pragma unroll
  for (int p = 0; p < 4; ++p){
    int lin = p*256 + t, d = lin >> 3, ch = lin & 7;
    u16x8 r;
    #pragma unroll
    for (int j = 0; j < 8; ++j) r[j] = Ls[(ch*8 + j)*136 + d];
    *(uint4*)(vT + (size_t)h*HD*LSEQ + (size_t)d*LSEQ + m0 + ch*8) =
      __builtin_bit_cast(uint4, r);
  }
}

// ---------------- flash attention: per (head, 64 q), online softmax over 32-key chunks ----------------
__global__ __launch_bounds__(256)
void attn_k(const unsigned short* __restrict__ qkv,
            const unsigned short* __restrict__ vT,
            unsigned short* __restrict__ x2)
{
  __shared__ __align__(16) unsigned short Ks[32*136];   // [key][d], pad->2-way only
  __shared__ __align__(16) unsigned short Vt[128*40];   // [d][m], pad 32->40
  __shared__ __align__(16) unsigned short Ps[4*16*40];  // per-wave P round-trip
  const int h = blockIdx.y, qb = blockIdx.x*64;
  const int t = threadIdx.x, w = t >> 6, lane = t & 63, quad = lane >> 4, l16 = lane & 15;

  bf16x8 aq[4];
  {
    const unsigned short* qp = qkv + (size_t)(qb + w*16 + l16)*QKVW + h*HD;
    #pragma unroll
    for (int dt = 0; dt < 4; ++dt)
      aq[dt] = __builtin_bit_cast(bf16x8, *(const uint4*)(qp + dt*32 + quad*8));
  }
  f32x4 o[8];
  #pragma unroll
  for (int i = 0; i < 8; ++i) o[i] = (f32x4){0.f,0.f,0.f,0.f};
  float mr[4] = {-1e30f,-1e30f,-1e30f,-1e30f};
  float lr[4] = {0.f,0.f,0.f,0.f};

  const unsigned short* kb = qkv + HID + h*HD;          // + key*QKVW
  const unsigned short* vb = vT + (size_t)h*HD*LSEQ;    // + d*LSEQ + m
  unsigned short* pw = &Ps[w*16*40];

  for (int m0 = 0; m0 < LSEQ; m0 += 32){
    __syncthreads();
    #pragma unroll
    for (int p = 0; p < 2; ++p){
      int lin = p*256 + t, kr = lin >> 4, ch = lin & 15;
      *(uint4*)&Ks[kr*136 + ch*8] = *(const uint4*)(kb + (size_t)(m0+kr)*QKVW + ch*8);
    }
    #pragma unroll
    for (int p = 0; p < 2; ++p){
      int lin = p*256 + t, d = lin >> 2, ch = lin & 3;
      *(uint4*)&Vt[d*40 + ch*8] = *(const uint4*)(vb + (size_t)d*LSEQ + m0 + ch*8);
    }
    __syncthreads();

    f32x4 s0 = (f32x4){0.f,0.f,0.f,0.f}, s1 = s0;
    #pragma unroll
    for (int dt = 0; dt < 4; ++dt){
      bf16x8 k0 = __builtin_bit_cast(bf16x8, *(const uint4*)&Ks[l16*136 + dt*32 + quad*8]);
      bf16x8 k1 = __builtin_bit_cast(bf16x8, *(const uint4*)&Ks[(16+l16)*136 + dt*32 + quad*8]);
      s0 = MFMA(aq[dt], k0, s0);
      s1 = MFMA(aq[dt], k1, s1);
    }
    // online softmax; S rows live in quads (row = quad*4+r), cols = l16
    #pragma unroll
    for (int r = 0; r < 4; ++r){
      float mx = fmaxf(s0[r], s1[r]);
      mx = fmaxf(mx, __shfl_xor(mx, 1));
      mx = fmaxf(mx, __shfl_xor(mx, 2));
      mx = fmaxf(mx, __shfl_xor(mx, 4));
      mx = fmaxf(mx, __shfl_xor(mx, 8));
      float mn = fmaxf(mr[r], mx);
      float al = __expf(mr[r] - mn);
      float p0 = __expf(s0[r] - mn), p1 = __expf(s1[r] - mn);
      float rs = p0 + p1;
      rs += __shfl_xor(rs, 1);
      rs += __shfl_xor(rs, 2);
      rs += __shfl_xor(rs, 4);
      rs += __shfl_xor(rs, 8);
      lr[r] = lr[r]*al + rs;
      mr[r] = mn;
      #pragma unroll
      for (int i = 0; i < 8; ++i) o[i][r] *= al;
      int q = quad*4 + r;
      pw[q*40 + l16]      = f2b(p0);
      pw[q*40 + 16 + l16] = f2b(p1);
    }
    // P: C-layout -> A-layout via per-wave LDS round-trip
    bf16x8 pa = __builtin_bit_cast(bf16x8, *(const uint4*)&pw[l16*40 + quad*8]);
    #pragma unroll
    for (int i = 0; i < 8; ++i){
      bf16x8 vv = __builtin_bit_cast(bf16x8, *(const uint4*)&Vt[(i*16 + l16)*40 + quad*8]);
      o[i] = MFMA(pa, vv, o[i]);
    }
  }
  #pragma unroll
  for (int i = 0; i < 8; ++i){
    #pragma unroll
    for (int r = 0; r < 4; ++r){
      int q = qb + w*16 + quad*4 + r;
      x2[(size_t)q*X2W + h*HD + i*16 + l16] = f2b(o[i][r] / lr[r]);
    }
  }
}

// ---------------- launch ----------------
extern "C" void kernel_launch(void* const* d_in, const int* in_sizes, int n_in,
                              void* d_out, int out_size, void* d_ws, size_t ws_size,
                              hipStream_t stream) {
  const float* hs     = (const float*)d_in[0];
  const float* temb   = (const float*)d_in[1];
  const float* cosp   = (const float*)d_in[2];
  const float* sinp   = (const float*)d_in[3];
  const float* ada_w  = (const float*)d_in[4];
  const float* ada_b  = (const float*)d_in[5];
  const float* lin1_w = (const float*)d_in[6];
  const float* lin1_b = (const float*)d_in[7];
  const float* lin2_w = (const float*)d_in[8];
  const float* lin2_b = (const float*)d_in[9];
  const float* qn     = (const float*)d_in[10];
  const float* kn     = (const float*)d_in[11];
  const int*   txt    = (const int*)d_in[12];
  float* out = (float*)d_out;

  char* ws = (char*)d_ws;
  float*          st  = (float*)ws;                     // 12288 B
  float*          emb = (float*)(ws + 12288);           // 36864 B
  unsigned short* nx  = (unsigned short*)(ws + 49152);       // 14155776 B
  unsigned short* qkv = (unsigned short*)(ws + 14204928);    // 42467328 B
  unsigned short* x2  = (unsigned short*)(ws + 56672256);    // 70778880 B
  unsigned short* vT  = (unsigned short*)(ws + 127451136);   // 14155776 B -> end 141606912

  silu_k<<<12, 256, 0, stream>>>(temb, st);
  ada_k<<<288, 256, 0, stream>>>(st, ada_w, ada_b, emb);
  ln_k<<<LSEQ, 256, 0, stream>>>(hs, emb, nx);
  gemm_k<1><<<dim3(N1/128, LSEQ/128), 256, 0, stream>>>(nx, lin1_w, lin1_b, HID, N1,
                                                        qkv, x2, nullptr, nullptr, nullptr);
  qknorm_k<<<(2*NH*LSEQ)/4, 256, 0, stream>>>(qkv, qn, kn, cosp, sinp, txt);
  vtrans_k<<<dim3(LSEQ/64, NH), 256, 0, stream>>>(qkv, vT);
  attn_k<<<dim3(LSEQ/64, NH), 256, 0, stream>>>(qkv, vT, x2);
  gemm_k<2><<<dim3(HID/128, LSEQ/128), 256, 0, stream>>>(x2, lin2_w, lin2_b, X2W, HID,
                                                         nullptr, nullptr, out, hs, emb);
}

// Round 2
// 1955.210 us; speedup vs baseline: 1.2239x; 1.2239x over previous
//
#include <hip/hip_runtime.h>
#include <stdint.h>

// ---- problem constants ----
#define HID   3072
#define LSEQ  2304
#define NH    24
#define HD    128
#define N1    21504   // 3*HID + MLP
#define QKVW  9216    // 3*HID
#define X2W   15360   // HID + MLP

typedef __bf16 bf16x8 __attribute__((ext_vector_type(8)));
typedef unsigned short u16x8 __attribute__((ext_vector_type(8)));
typedef float f32x4 __attribute__((ext_vector_type(4)));

#define MFMA(a,b,c) __builtin_amdgcn_mfma_f32_16x16x32_bf16((a),(b),(c),0,0,0)

// async global->LDS, 16B per lane; LDS dest = wave-uniform base + lane*16
#define GLOAD_LDS16(g, l) __builtin_amdgcn_global_load_lds( \
    (const __attribute__((address_space(1))) unsigned int*)(g), \
    (__attribute__((address_space(3))) unsigned int*)(l), 16, 0, 0)

__device__ __forceinline__ unsigned short f2b(float f){
  unsigned int u = __builtin_bit_cast(unsigned int, f);
  u += 0x7fffu + ((u >> 16) & 1u);   // RTNE
  return (unsigned short)(u >> 16);
}
__device__ __forceinline__ float b2f(unsigned short b){
  return __builtin_bit_cast(float, ((unsigned int)b) << 16);
}
__device__ __forceinline__ unsigned int pk2(float lo, float hi){
  return (unsigned int)f2b(lo) | ((unsigned int)f2b(hi) << 16);
}

// ---------------- silu(temb) ----------------
__global__ void silu_k(const float* __restrict__ temb, float* __restrict__ st){
  int i = blockIdx.x*256 + threadIdx.x;
  if (i < HID){ float x = temb[i]; st[i] = x / (1.f + __expf(-x)); }
}

// ---------------- emb = silu(temb) @ ada_w + ada_b ----------------
__global__ __launch_bounds__(256) void ada_k(const float* __restrict__ st,
                                             const float* __restrict__ aw,
                                             const float* __restrict__ ab,
                                             float* __restrict__ emb){
  int c = threadIdx.x & 31, g = threadIdx.x >> 5;
  int col = blockIdx.x*32 + c;
  float acc = 0.f;
  for (int k = g; k < HID; k += 8)
    acc += st[k] * aw[(size_t)k*QKVW + col];
  __shared__ float part[256];
  part[threadIdx.x] = acc;
  __syncthreads();
  if (threadIdx.x < 32){
    float s = 0.f;
    #pragma unroll
    for (int j = 0; j < 8; ++j) s += part[j*32 + threadIdx.x];
    int cc = blockIdx.x*32 + threadIdx.x;
    emb[cc] = s + ab[cc];
  }
}

// ---------------- LayerNorm + (1+scale)/shift modulation -> bf16 ----------------
__global__ __launch_bounds__(256) void ln_k(const float* __restrict__ hs,
                                            const float* __restrict__ emb,
                                            unsigned short* __restrict__ nx){
  int l = blockIdx.x, t = threadIdx.x;
  const float* row = hs + (size_t)l*HID;
  float x[12], s = 0.f, ss = 0.f;
  #pragma unroll
  for (int i = 0; i < 12; ++i){ x[i] = row[t + i*256]; s += x[i]; ss += x[i]*x[i]; }
  #pragma unroll
  for (int off = 32; off; off >>= 1){ s += __shfl_xor(s, off); ss += __shfl_xor(ss, off); }
  __shared__ float red[8];
  int w = t >> 6, lane = t & 63;
  if (!lane){ red[w] = s; red[4+w] = ss; }
  __syncthreads();
  s = red[0]+red[1]+red[2]+red[3];
  ss = red[4]+red[5]+red[6]+red[7];
  float mu = s * (1.f/HID);
  float var = ss * (1.f/HID) - mu*mu;
  float rstd = rsqrtf(var + 1e-6f);
  #pragma unroll
  for (int i = 0; i < 12; ++i){
    int c = t + i*256;
    float v = (x[i]-mu)*rstd*(1.f + emb[HID + c]) + emb[c];
    nx[(size_t)l*HID + c] = f2b(v);
  }
}

// ---------------- weight convert+transpose: W fp32 [K rows][ldw cols] -> WT bf16 [n][K] ----------------
// 64(K) x 64(N) tile per block; both global sides fully coalesced.
__global__ __launch_bounds__(256) void tconv_k(const float* __restrict__ W,
                                               unsigned short* __restrict__ WT,
                                               int ldw, int K){
  __shared__ unsigned short Ls[64*66];
  int k0 = blockIdx.x*64, n0 = blockIdx.y*64;
  int t = threadIdx.x;
  #pragma unroll
  for (int p = 0; p < 4; ++p){
    int idx = p*256 + t, row = idx >> 4, c4 = idx & 15;
    float4 f = *(const float4*)(W + (size_t)(k0+row)*ldw + n0 + c4*4);
    *(unsigned int*)&Ls[row*66 + c4*4]     = pk2(f.x, f.y);
    *(unsigned int*)&Ls[row*66 + c4*4 + 2] = pk2(f.z, f.w);
  }
  __syncthreads();
  #pragma unroll
  for (int p = 0; p < 2; ++p){
    int idx = p*256 + t, n = idx >> 3, ch = idx & 7;
    u16x8 r;
    #pragma unroll
    for (int j = 0; j < 8; ++j) r[j] = Ls[(ch*8 + j)*66 + n];
    *(uint4*)(WT + (size_t)(n0+n)*K + k0 + ch*8) = __builtin_bit_cast(uint4, r);
  }
}

// ---------------- m97-style MFMA GEMM: C = A(bf16 [M][K]) @ BT(bf16 [N][K])^T + bias ----------------
// EPI=1: qkv cols (write bf16 to o16[gm*QKVW + gn])
// EPI=3: mlp cols (gelu -> o16[gm*X2W + HID + gn])
// EPI=2: final (of[gm*HID+gn] = hid + v*gate)
template<int EPI>
__global__ __launch_bounds__(256)
void gemm_k(const unsigned short* __restrict__ A, const unsigned short* __restrict__ BT,
            const float* __restrict__ bias, int K,
            unsigned short* __restrict__ o16, float* __restrict__ of,
            const float* __restrict__ hid, const float* __restrict__ emb)
{
  __shared__ __align__(16) unsigned short As[128*32];   // [m][k]
  __shared__ __align__(16) unsigned short Bs[128*32];   // [n][k]
  const int t = threadIdx.x;
  const int m0 = blockIdx.y * 128, n0 = blockIdx.x * 128;
  const int w = t >> 6, lane = t & 63, quad = lane >> 4, l16 = lane & 15;
  const int wm = w >> 1, wn = w & 1;

  f32x4 acc[4][4];
  #pragma unroll
  for (int i = 0; i < 4; ++i)
    #pragma unroll
    for (int j = 0; j < 4; ++j) acc[i][j] = (f32x4){0.f,0.f,0.f,0.f};

  // staging map: wave w round r covers rows (w*2+r)*16 .. +15, lane -> (row=lane/4, kch=(lane&3)*8)
  const unsigned short* aG = A  + (size_t)(m0 + w*32 + (lane>>2))*K + (lane&3)*8;
  const unsigned short* bG = BT + (size_t)(n0 + w*32 + (lane>>2))*K + (lane&3)*8;
  unsigned short* aL = &As[w*1024];
  unsigned short* bL = &Bs[w*1024];

  for (int k0 = 0; k0 < K; k0 += 32){
    __syncthreads();
    GLOAD_LDS16(aG + k0,          aL);
    GLOAD_LDS16(aG + 16*K + k0,   aL + 512);
    GLOAD_LDS16(bG + k0,          bL);
    GLOAD_LDS16(bG + 16*K + k0,   bL + 512);
    __syncthreads();

    bf16x8 af[4], bf[4];
    #pragma unroll
    for (int mt = 0; mt < 4; ++mt)
      af[mt] = __builtin_bit_cast(bf16x8, *(const uint4*)&As[(wm*64 + mt*16 + l16)*32 + quad*8]);
    #pragma unroll
    for (int nt = 0; nt < 4; ++nt)
      bf[nt] = __builtin_bit_cast(bf16x8, *(const uint4*)&Bs[(wn*64 + nt*16 + l16)*32 + quad*8]);
    #pragma unroll
    for (int mt = 0; mt < 4; ++mt)
      #pragma unroll
      for (int nt = 0; nt < 4; ++nt)
        acc[mt][nt] = MFMA(af[mt], bf[nt], acc[mt][nt]);
  }

  // epilogue (C/D layout: col = lane&15, row = quad*4 + r)
  #pragma unroll
  for (int mt = 0; mt < 4; ++mt){
    #pragma unroll
    for (int nt = 0; nt < 4; ++nt){
      const int gn = n0 + wn*64 + nt*16 + l16;
      const float bs = bias[gn];
      #pragma unroll
      for (int r = 0; r < 4; ++r){
        const int gm = m0 + wm*64 + mt*16 + quad*4 + r;
        float v = acc[mt][nt][r] + bs;
        if (EPI == 1){
          o16[(size_t)gm*QKVW + gn] = f2b(v);
        } else if (EPI == 3){
          float e = __expf(1.5957691216057308f*(v + 0.044715f*v*v*v));
          float th = 1.f - 2.f/(e + 1.f);
          o16[(size_t)gm*X2W + HID + gn] = f2b(0.5f*v*(1.f + th));
        } else {
          of[(size_t)gm*HID + gn] = hid[(size_t)gm*HID + gn] + v * emb[2*HID + gn];
        }
      }
    }
  }
}

// ---------------- q/k RMSNorm + RoPE (in place on qkv), fold 1/sqrt(HD) into q ----------------
__global__ __launch_bounds__(256) void qknorm_k(unsigned short* __restrict__ qkv,
                                                const float* __restrict__ qn,
                                                const float* __restrict__ kn,
                                                const float* __restrict__ cosp,
                                                const float* __restrict__ sinp,
                                                const int* __restrict__ txtp){
  int img = LSEQ - txtp[0];
  int rid = blockIdx.x*4 + (threadIdx.x >> 6);
  int lane = threadIdx.x & 63;
  int which = rid / (NH*LSEQ);
  int rem   = rid % (NH*LSEQ);
  int h = rem / LSEQ, l = rem % LSEQ;
  unsigned short* p = qkv + (size_t)l*QKVW + which*HID + h*HD + lane*2;
  unsigned int both = *(const unsigned int*)p;
  float x0 = b2f((unsigned short)(both & 0xffffu));
  float x1 = b2f((unsigned short)(both >> 16));
  float ss = x0*x0 + x1*x1;
  #pragma unroll
  for (int off = 32; off; off >>= 1) ss += __shfl_xor(ss, off);
  float r = rsqrtf(ss*(1.f/HD) + 1e-6f);
  const float* wv = which ? kn : qn;
  float y0 = x0*r*wv[lane*2], y1 = x1*r*wv[lane*2+1];
  if (l < img){
    float c0 = cosp[l*HD + lane*2], c1 = cosp[l*HD + lane*2 + 1];
    float s0 = sinp[l*HD + lane*2], s1 = sinp[l*HD + lane*2 + 1];
    float t0 = y0*c0 - y1*s0;
    float t1 = y1*c1 + y0*s1;
    y0 = t0; y1 = t1;
  }
  if (which == 0){ y0 *= 0.08838834764831845f; y1 *= 0.08838834764831845f; }
  *(unsigned int*)p = pk2(y0, y1);
}

// ---------------- V transpose: qkv v-part [l][h*128+d] -> vT[h][d][l] ----------------
__global__ __launch_bounds__(256) void vtrans_k(const unsigned short* __restrict__ qkv,
                                                unsigned short* __restrict__ vT){
  __shared__ __align__(16) unsigned short Ls[64*136];
  int h = blockIdx.y, m0 = blockIdx.x*64, t = threadIdx.x;
  #pragma unroll
  for (int p = 0; p < 4; ++p){
    int lin = p*256 + t, m = lin >> 4, ch = lin & 15;
    *(uint4*)&Ls[m*136 + ch*8] =
      *(const uint4*)(qkv + (size_t)(m0+m)*QKVW + 2*HID + h*HD + ch*8);
  }
  __syncthreads();
  #pragma unroll
  for (int p = 0; p < 4; ++p){
    int lin = p*256 + t, d = lin >> 3, ch = lin & 7;
    u16x8 r;
    #pragma unroll
    for (int j = 0; j < 8; ++j) r[j] = Ls[(ch*8 + j)*136 + d];
    *(uint4*)(vT + (size_t)h*HD*LSEQ + (size_t)d*LSEQ + m0 + ch*8) =
      __builtin_bit_cast(uint4, r);
  }
}

// ---------------- flash attention: per (head, 64 q), online softmax over 32-key chunks ----------------
__global__ __launch_bounds__(256)
void attn_k(const unsigned short* __restrict__ qkv,
            const unsigned short* __restrict__ vT,
            unsigned short* __restrict__ x2)
{
  __shared__ __align__(16) unsigned short Ks[32*136];   // [key][d]
  __shared__ __align__(16) unsigned short Vt[128*40];   // [d][m]
  __shared__ __align__(16) unsigned short Ps[4*16*40];  // per-wave P round-trip
  const int h = blockIdx.y, qb = blockIdx.x*64;
  const int t = threadIdx.x, w = t >> 6, lane = t & 63, quad = lane >> 4, l16 = lane & 15;

  bf16x8 aq[4];
  {
    const unsigned short* qp = qkv + (size_t)(qb + w*16 + l16)*QKVW + h*HD;
    #pragma unroll
    for (int dt = 0; dt < 4; ++dt)
      aq[dt] = __builtin_bit_cast(bf16x8, *(const uint4*)(qp + dt*32 + quad*8));
  }
  f32x4 o[8];
  #pragma unroll
  for (int i = 0; i < 8; ++i) o[i] = (f32x4){0.f,0.f,0.f,0.f};
  float mr[4] = {-1e30f,-1e30f,-1e30f,-1e30f};
  float lr[4] = {0.f,0.f,0.f,0.f};

  const unsigned short* kb = qkv + HID + h*HD;
  const unsigned short* vb = vT + (size_t)h*HD*LSEQ;
  unsigned short* pw = &Ps[w*16*40];

  for (int m0 = 0; m0 < LSEQ; m0 += 32){
    __syncthreads();
    #pragma unroll
    for (int p = 0; p < 2; ++p){
      int lin = p*256 + t, kr = lin >> 4, ch = lin & 15;
      *(uint4*)&Ks[kr*136 + ch*8] = *(const uint4*)(kb + (size_t)(m0+kr)*QKVW + ch*8);
    }
    #pragma unroll
    for (int p = 0; p < 2; ++p){
      int lin = p*256 + t, d = lin >> 2, ch = lin & 3;
      *(uint4*)&Vt[d*40 + ch*8] = *(const uint4*)(vb + (size_t)d*LSEQ + m0 + ch*8);
    }
    __syncthreads();

    f32x4 s0 = (f32x4){0.f,0.f,0.f,0.f}, s1 = s0;
    #pragma unroll
    for (int dt = 0; dt < 4; ++dt){
      bf16x8 k0 = __builtin_bit_cast(bf16x8, *(const uint4*)&Ks[l16*136 + dt*32 + quad*8]);
      bf16x8 k1 = __builtin_bit_cast(bf16x8, *(const uint4*)&Ks[(16+l16)*136 + dt*32 + quad*8]);
      s0 = MFMA(aq[dt], k0, s0);
      s1 = MFMA(aq[dt], k1, s1);
    }
    #pragma unroll
    for (int r = 0; r < 4; ++r){
      float mx = fmaxf(s0[r], s1[r]);
      mx = fmaxf(mx, __shfl_xor(mx, 1));
      mx = fmaxf(mx, __shfl_xor(mx, 2));
      mx = fmaxf(mx, __shfl_xor(mx, 4));
      mx = fmaxf(mx, __shfl_xor(mx, 8));
      float mn = fmaxf(mr[r], mx);
      float al = __expf(mr[r] - mn);
      float p0 = __expf(s0[r] - mn), p1 = __expf(s1[r] - mn);
      float rs = p0 + p1;
      rs += __shfl_xor(rs, 1);
      rs += __shfl_xor(rs, 2);
      rs += __shfl_xor(rs, 4);
      rs += __shfl_xor(rs, 8);
      lr[r] = lr[r]*al + rs;
      mr[r] = mn;
      #pragma unroll
      for (int i = 0; i < 8; ++i) o[i][r] *= al;
      int q = quad*4 + r;
      pw[q*40 + l16]      = f2b(p0);
      pw[q*40 + 16 + l16] = f2b(p1);
    }
    bf16x8 pa = __builtin_bit_cast(bf16x8, *(const uint4*)&pw[l16*40 + quad*8]);
    #pragma unroll
    for (int i = 0; i < 8; ++i){
      bf16x8 vv = __builtin_bit_cast(bf16x8, *(const uint4*)&Vt[(i*16 + l16)*40 + quad*8]);
      o[i] = MFMA(pa, vv, o[i]);
    }
  }
  #pragma unroll
  for (int i = 0; i < 8; ++i){
    #pragma unroll
    for (int r = 0; r < 4; ++r){
      int q = qb + w*16 + quad*4 + r;
      x2[(size_t)q*X2W + h*HD + i*16 + l16] = f2b(o[i][r] / lr[r]);
    }
  }
}

// ---------------- launch ----------------
extern "C" void kernel_launch(void* const* d_in, const int* in_sizes, int n_in,
                              void* d_out, int out_size, void* d_ws, size_t ws_size,
                              hipStream_t stream) {
  const float* hs     = (const float*)d_in[0];
  const float* temb   = (const float*)d_in[1];
  const float* cosp   = (const float*)d_in[2];
  const float* sinp   = (const float*)d_in[3];
  const float* ada_w  = (const float*)d_in[4];
  const float* ada_b  = (const float*)d_in[5];
  const float* lin1_w = (const float*)d_in[6];
  const float* lin1_b = (const float*)d_in[7];
  const float* lin2_w = (const float*)d_in[8];
  const float* lin2_b = (const float*)d_in[9];
  const float* qn     = (const float*)d_in[10];
  const float* kn     = (const float*)d_in[11];
  const int*   txt    = (const int*)d_in[12];
  float* out = (float*)d_out;

  char* ws = (char*)d_ws;
  float*          st  = (float*)ws;                          // 12,288 B
  float*          emb = (float*)(ws + 12288);                // 36,864 B
  unsigned short* nx  = (unsigned short*)(ws + 49152);       // 14,155,776 B
  unsigned short* qkv = (unsigned short*)(ws + 14204928);    // 42,467,328 B
  unsigned short* x2  = (unsigned short*)(ws + 56672256);    // 70,778,880 B
  unsigned short* vT  = (unsigned short*)(ws + 127451136);   // 14,155,776 B
  unsigned short* wt  = (unsigned short*)(ws + 141606912);   // 94,371,840 B -> end 235,978,752

  silu_k<<<12, 256, 0, stream>>>(temb, st);
  ada_k<<<288, 256, 0, stream>>>(st, ada_w, ada_b, emb);
  ln_k<<<LSEQ, 256, 0, stream>>>(hs, emb, nx);

  // lin1, qkv half: convert cols 0..9215 then GEMM
  tconv_k<<<dim3(HID/64, QKVW/64), 256, 0, stream>>>(lin1_w, wt, N1, HID);
  gemm_k<1><<<dim3(QKVW/128, LSEQ/128), 256, 0, stream>>>(nx, wt, lin1_b, HID,
                                                          qkv, nullptr, nullptr, nullptr);
  // lin1, mlp half: convert cols 9216..21503 then GEMM (gelu epilogue into x2)
  tconv_k<<<dim3(HID/64, (N1-QKVW)/64), 256, 0, stream>>>(lin1_w + QKVW, wt, N1, HID);
  gemm_k<3><<<dim3((N1-QKVW)/128, LSEQ/128), 256, 0, stream>>>(nx, wt, lin1_b + QKVW, HID,
                                                               x2, nullptr, nullptr, nullptr);

  qknorm_k<<<(2*NH*LSEQ)/4, 256, 0, stream>>>(qkv, qn, kn, cosp, sinp, txt);
  vtrans_k<<<dim3(LSEQ/64, NH), 256, 0, stream>>>(qkv, vT);
  attn_k<<<dim3(LSEQ/64, NH), 256, 0, stream>>>(qkv, vT, x2);

  // lin2: convert [15360][3072] -> [3072][15360] then GEMM (gate+residual epilogue)
  tconv_k<<<dim3(X2W/64, HID/64), 256, 0, stream>>>(lin2_w, wt, HID, X2W);
  gemm_k<2><<<dim3(HID/128, LSEQ/128), 256, 0, stream>>>(x2, wt, lin2_b, X2W,
                                                         nullptr, out, hs, emb);
}